// Round 12
// baseline (348.451 us; speedup 1.0000x reference)
//
#include <hip/hip_runtime.h>
#include <hip/hip_bf16.h>
#include <cstdint>

#define H 128
#define VV 100
#define CC 1000
#define ER_N 250
#define NODE_IN_N 82
#define EDGE_IN_N 6
#define LDA 136     // bf16 row stride: 272B rows, b128-aligned, 2-way banks (free)
#define NT 512      // 8 waves per block; 2 blocks/CU (LDS ~68KB, VGPR<=128)

typedef short short8 __attribute__((ext_vector_type(8)));
typedef float floatx4 __attribute__((ext_vector_type(4)));
typedef __hip_bfloat16 bf16;

// ---- shared memory layout (manual offsets, 16B aligned)
#define OFF_B0 0
#define OFF_B1 27200
#define OFF_EF 54400
#define OFF_RP 62400
#define OFF_CNT 62816
#define OFF_SD 63232
#define OFF_EIDX 64240
#define OFF_RED 65248
#define OFF_G 67296
#define SMEM_TOTAL 67808

// ================= prep: weights -> B-frag bf16 + flag reset (tiny) =================
#define PREP_W (27 * 4096)
__global__ __launch_bounds__(256) void prep_w(
    const float* __restrict__ Wp, const float* __restrict__ Wm,
    const float* __restrict__ Wn, const float* __restrict__ Wmd,
    const float* __restrict__ Wnd, bf16* __restrict__ wfrag,
    int* __restrict__ flag) {
  int idx = blockIdx.x * 256 + threadIdx.x;
  if (idx == 0) *flag = 0;  // hr-ready flag: ws is poisoned each call, must re-zero
  if (idx >= PREP_W) return;
  const float* W;
  int Ksrc, local = idx;
  if (idx < 3 * 4096)       { W = Wp;  Ksrc = NODE_IN_N; }
  else if (idx < 7 * 4096)  { W = Wm;  Ksrc = H;     local -= 3 * 4096; }
  else if (idx < 15 * 4096) { W = Wn;  Ksrc = 2 * H; local -= 7 * 4096; }
  else if (idx < 19 * 4096) { W = Wmd; Ksrc = H;     local -= 15 * 4096; }
  else                      { W = Wnd; Ksrc = 2 * H; local -= 19 * 4096; }
  int j = local & 7, lane = (local >> 3) & 63, nt = (local >> 9) & 7, kc = local >> 12;
  int k = kc * 32 + ((lane >> 4) & 3) * 8 + j;
  int n = nt * 16 + (lane & 15);
  float v = (k < Ksrc) ? W[(size_t)k * H + n] : 0.f;
  wfrag[idx] = __float2bfloat16(v);
}

// ====== GEMM helpers: wave = (mh<<2)|gh ; mh: m-tiles {0..3}/{4..6}, gh: n-pair =====
template<int CHUNKS>
__device__ __forceinline__ void load_b2(short8 b[2][CHUNKS], const bf16* __restrict__ Wf,
                                        int gh, int lane) {
#pragma unroll
  for (int kc = 0; kc < CHUNKS; ++kc) {
    b[0][kc] = *(const short8*)(Wf + ((size_t)((kc * 8 + 2 * gh + 0) * 64 + lane)) * 8);
    b[1][kc] = *(const short8*)(Wf + ((size_t)((kc * 8 + 2 * gh + 1) * 64 + lane)) * 8);
  }
}

// A-frag read once, feeds two MFMAs (halves A-LDS traffic vs n-solo mapping)
template<int CHUNKS>
__device__ __forceinline__ void mfma_g(floatx4 acc[4][2], const short8 b[2][CHUNKS],
                                       const bf16* A, int m0, int mc,
                                       int l16, int quad) {
#pragma unroll
  for (int kc = 0; kc < CHUNKS; ++kc)
#pragma unroll
    for (int mi = 0; mi < 4; ++mi)
      if (mi < mc) {
        short8 a = *(const short8*)(A + ((m0 + mi) * 16 + l16) * LDA + kc * 32 + quad * 8);
        acc[mi][0] = __builtin_amdgcn_mfma_f32_16x16x32_bf16(a, b[0][kc], acc[mi][0], 0, 0, 0);
        acc[mi][1] = __builtin_amdgcn_mfma_f32_16x16x32_bf16(a, b[1][kc], acc[mi][1], 0, 0, 0);
      }
}

__device__ __forceinline__ void epi2(floatx4 acc[4][2], const float* __restrict__ bias,
                                     bool relu, bf16* Out,
                                     int gh, int m0, int mc, int quad, int l16) {
#pragma unroll
  for (int nn = 0; nn < 2; ++nn) {
    int col = (2 * gh + nn) * 16 + l16;
    float bb = bias[col];
#pragma unroll
    for (int mi = 0; mi < 4; ++mi)
      if (mi < mc)
#pragma unroll
        for (int r = 0; r < 4; ++r) {
          int row = (m0 + mi) * 16 + quad * 4 + r;
          if (row < VV) {
            float v = acc[mi][nn][r] + bb;
            if (relu) v = fmaxf(v, 0.f);
            Out[row * LDA + col] = __float2bfloat16(v);
          }
        }
  }
}

__device__ __forceinline__ void zero42(floatx4 acc[4][2]) {
#pragma unroll
  for (int mi = 0; mi < 4; ++mi) {
    acc[mi][0] = (floatx4){0.f, 0.f, 0.f, 0.f};
    acc[mi][1] = (floatx4){0.f, 0.f, 0.f, 0.f};
  }
}

// gather: thread (node q8+8i, col-pair c2) reads t(Y), writes agg directly into X
__device__ __forceinline__ void gather(const bf16* Y, bf16* X, const float* sEf,
                                       const int* sRowPtr, const int* sEidx,
                                       const float* __restrict__ WmBot,
                                       int q8, int c2) {
  float wb[EDGE_IN_N][2];
#pragma unroll
  for (int k = 0; k < EDGE_IN_N; ++k) {
    float2 w2 = *(const float2*)&WmBot[k * H + 2 * c2];
    wb[k][0] = w2.x;
    wb[k][1] = w2.y;
  }
#pragma unroll
  for (int i = 0; i < 13; ++i) {
    int n = q8 + 8 * i;
    if (n < VV) {
      int p0 = sRowPtr[n], p1 = sRowPtr[n + 1];
      float a0 = 0.f, a1 = 0.f;
      for (int p = p0; p < p1; ++p) {
        int v = sEidx[p];
        int s = v & 127, e = v >> 7;
        uint32_t tt = *(const uint32_t*)&Y[s * LDA + 2 * c2];
        float u0 = __uint_as_float((tt & 0xffffu) << 16);
        float u1 = __uint_as_float((tt >> 16) << 16);
        float4 ea = *(const float4*)&sEf[e * 8];
        float2 eb = *(const float2*)&sEf[e * 8 + 4];
        u0 = fmaf(ea.x, wb[0][0], u0); u1 = fmaf(ea.x, wb[0][1], u1);
        u0 = fmaf(ea.y, wb[1][0], u0); u1 = fmaf(ea.y, wb[1][1], u1);
        u0 = fmaf(ea.z, wb[2][0], u0); u1 = fmaf(ea.z, wb[2][1], u1);
        u0 = fmaf(ea.w, wb[3][0], u0); u1 = fmaf(ea.w, wb[3][1], u1);
        u0 = fmaf(eb.x, wb[4][0], u0); u1 = fmaf(eb.x, wb[4][1], u1);
        u0 = fmaf(eb.y, wb[5][0], u0); u1 = fmaf(eb.y, wb[5][1], u1);
        a0 += fmaxf(u0, 0.f);
        a1 += fmaxf(u1, 0.f);
      }
      __hip_bfloat162 pk;
      pk.x = __float2bfloat16(a0);
      pk.y = __float2bfloat16(a1);
      *(__hip_bfloat162*)&X[n * LDA + 2 * c2] = pk;
    }
  }
}

// one WLN layer: h in X on entry, h_new in Y on exit (caller swaps). 4 barriers.
__device__ __forceinline__ void wln_layer(
    bf16* X, bf16* Y, const float* sEf, const int* sRowPtr, const int* sEidx,
    const bf16* __restrict__ wf_msg, const float* __restrict__ bmsg,
    const float* __restrict__ WmBot,
    const bf16* __restrict__ wf_new, const float* __restrict__ bnew,
    int lane, int gh, int m0, int mc, int quad, int l16, int q8, int c2) {
  short8 bm_[2][4], bu1[2][4], bu2[2][4];
  floatx4 accM[4][2], accU[4][2];
  // P1: msg GEMM t = h @ Wm_top + bm -> Y
  load_b2<4>(bm_, wf_msg, gh, lane);
  zero42(accM);
  mfma_g<4>(accM, bm_, X, m0, mc, l16, quad);
  load_b2<4>(bu1, wf_new, gh, lane);            // prefetch upd-h B
  epi2(accM, bmsg, false, Y, gh, m0, mc, quad, l16);
  __syncthreads();  // bar A: t visible
  // P2a: upd-h GEMM (reads X)
  zero42(accU);
  mfma_g<4>(accU, bu1, X, m0, mc, l16, quad);
  load_b2<4>(bu2, wf_new + 4 * 4096, gh, lane); // prefetch upd-agg B
  __syncthreads();  // bar B: all X reads complete
  // P2b: gather (reads Y, writes agg -> X)
  gather(Y, X, sEf, sRowPtr, sEidx, WmBot, q8, c2);
  __syncthreads();  // bar C: agg visible
  // P3: upd-agg GEMM, h_new -> Y (t dead)
  mfma_g<4>(accU, bu2, X, m0, mc, l16, quad);
  epi2(accU, bnew, true, Y, gh, m0, mc, quad, l16);
  __syncthreads();  // bar D: h_new visible
}

// grid = 1001: block 0 = reactant (publishes hr via agent-scope atomics + flag),
// blocks 1..1000 = products (spin on flag at the diff point only).
__global__ __launch_bounds__(NT, 4) void wln_fused(
    const float* __restrict__ Xr, const float* __restrict__ Ere,
    const int* __restrict__ rsrc, const int* __restrict__ rdst,
    const float* __restrict__ Xp, const float* __restrict__ Epe,
    const int* __restrict__ psrc, const int* __restrict__ pdst,
    const bf16* __restrict__ wf_proj, const float* __restrict__ bproj,
    const bf16* __restrict__ wf_msg, const float* __restrict__ bmsg,
    const float* __restrict__ WmBot,
    const bf16* __restrict__ wf_new, const float* __restrict__ bnew,
    const bf16* __restrict__ wf_msgd, const float* __restrict__ bmsgd,
    const float* __restrict__ WmdBot,
    const bf16* __restrict__ wf_newd, const float* __restrict__ bnewd,
    bf16* __restrict__ hr_global, int* __restrict__ flag,
    const float* __restrict__ W1, const float* __restrict__ b1,
    const float* __restrict__ W2, const float* __restrict__ b2,
    const float* __restrict__ scores, float* __restrict__ out) {
  __shared__ __align__(16) char smem[SMEM_TOTAL];
  bf16* sB0 = (bf16*)(smem + OFF_B0);
  bf16* sB1 = (bf16*)(smem + OFF_B1);
  float* sEf = (float*)(smem + OFF_EF);
  int* sRowPtr = (int*)(smem + OFF_RP);
  int* sCnt = (int*)(smem + OFF_CNT);
  int* sSD = (int*)(smem + OFF_SD);
  int* sEidx = (int*)(smem + OFF_EIDX);
  float* sRed = (float*)(smem + OFF_RED);
  float* sG = (float*)(smem + OFF_G);

  const int tid = threadIdx.x;
  const int lane = tid & 63;
  const int wave = tid >> 6;                // 0..7
  const int quad = (lane >> 4) & 3, l16 = lane & 15;
  const int gh = wave & 3, mh = wave >> 2;  // n-pair {2gh,2gh+1}; m-tiles mh*4..
  const int m0 = mh * 4, mc = mh ? 3 : 4;
  const int q8 = tid >> 6, c2 = tid & 63;
  const bool REAC = (blockIdx.x == 0);
  const int c = REAC ? 0 : (blockIdx.x - 1);
  const int no = c * VV;
  const long eo = (long)c * ER_N;

  // ---- stage edges + counts + edge feats + X (raw fp32 -> bf16) ----
  if (tid < VV) sCnt[tid] = 0;
  __syncthreads();
  if (tid < ER_N) {
    int s, d;
    if (REAC) { s = rsrc[tid]; d = rdst[tid]; }
    else      { s = psrc[eo + tid] - no; d = pdst[eo + tid] - no; }
    sSD[tid] = (d << 16) | s;
    atomicAdd(&sCnt[d], 1);
  }
  {
    const float* Xsrc = REAC ? Xr : (Xp + (size_t)no * NODE_IN_N);
    const float* Esrc = REAC ? Ere : (Epe + (size_t)eo * EDGE_IN_N);
    for (int f = tid; f < ER_N * EDGE_IN_N; f += NT) {
      int e = f / EDGE_IN_N, k = f - e * EDGE_IN_N;
      sEf[e * 8 + k] = Esrc[f];
    }
    for (int f = tid; f < VV * NODE_IN_N; f += NT) {
      int r = f / NODE_IN_N, cc = f - r * NODE_IN_N;
      sB0[r * LDA + cc] = __float2bfloat16(Xsrc[f]);
    }
    for (int f = tid; f < VV * 14; f += NT) {  // zero-pad cols 82..95
      int r = f / 14, cc = NODE_IN_N + (f - r * 14);
      sB0[r * LDA + cc] = __float2bfloat16(0.f);
    }
  }
  __syncthreads();

  // ---- single-wave shuffle scan (exclusive prefix over 100 counts) ----
  if (wave == 0) {
    int c0 = sCnt[lane];
    int c1 = (lane + 64 < VV) ? sCnt[lane + 64] : 0;
    int v = c0;
#pragma unroll
    for (int d = 1; d < 64; d <<= 1) {
      int t = __shfl_up(v, d, 64);
      if (lane >= d) v += t;
    }
    int total0 = __shfl(v, 63, 64);
    int w = c1;
#pragma unroll
    for (int d = 1; d < 64; d <<= 1) {
      int t = __shfl_up(w, d, 64);
      if (lane >= d) w += t;
    }
    int ex0 = v - c0;
    int ex1 = total0 + w - c1;
    sRowPtr[lane] = ex0;
    sCnt[lane] = ex0;
    if (lane + 64 < VV) {
      sRowPtr[lane + 64] = ex1;
      sCnt[lane + 64] = ex1;
    }
    if (lane == 0) sRowPtr[VV] = ER_N;
  }
  __syncthreads();
  if (tid < ER_N) {
    int sd = sSD[tid];
    int p = atomicAdd(&sCnt[sd >> 16], 1);
    sEidx[p] = (sd & 0xffff) | (tid << 7);
  }
  __syncthreads();

  // ---- input projection: h = relu(X @ Wproj + bproj) : sB0 -> sB1 ----
  {
    short8 bp_[2][3];
    floatx4 acc[4][2];
    load_b2<3>(bp_, wf_proj, gh, lane);
    zero42(acc);
    mfma_g<3>(acc, bp_, sB0, m0, mc, l16, quad);
    epi2(acc, bproj, true, sB1, gh, m0, mc, quad, l16);
  }
  __syncthreads();

  bf16* Hb = sB1;
  bf16* Tb = sB0;

  // ---- 3 shared-weight encoder layers (ping-pong) ----
  for (int l = 0; l < 3; ++l) {
    wln_layer(Hb, Tb, sEf, sRowPtr, sEidx, wf_msg, bmsg, WmBot, wf_new, bnew,
              lane, gh, m0, mc, quad, l16, q8, c2);
    bf16* tmp = Hb; Hb = Tb; Tb = tmp;
  }

  if (REAC) {
    // publish hr with agent-scope stores (visible across non-coherent XCD L2s)
    for (int f = tid; f < VV * H / 2; f += NT) {
      int r = f >> 6, j = (f & 63) * 2;
      uint32_t pk = *(const uint32_t*)&Hb[r * LDA + j];
      __hip_atomic_store((uint32_t*)hr_global + f, pk,
                         __ATOMIC_RELAXED, __HIP_MEMORY_SCOPE_AGENT);
    }
    __syncthreads();
    if (tid == 0)
      __hip_atomic_store(flag, 1, __ATOMIC_RELEASE, __HIP_MEMORY_SCOPE_AGENT);
    return;
  }

  // ---- wait for hr, then diff against broadcast reactant (in place on Hb) ----
  if (tid == 0) {
    while (__hip_atomic_load(flag, __ATOMIC_ACQUIRE, __HIP_MEMORY_SCOPE_AGENT) == 0)
      __builtin_amdgcn_s_sleep(16);
  }
  __syncthreads();
  for (int f = tid; f < VV * H / 2; f += NT) {
    int r = f >> 6, j = (f & 63) * 2;
    uint32_t rk = __hip_atomic_load((const uint32_t*)hr_global + f,
                                    __ATOMIC_RELAXED, __HIP_MEMORY_SCOPE_AGENT);
    uint32_t hk = *(const uint32_t*)&Hb[r * LDA + j];
    float h0 = __uint_as_float((hk & 0xffffu) << 16) -
               __uint_as_float((rk & 0xffffu) << 16);
    float h1 = __uint_as_float((hk >> 16) << 16) -
               __uint_as_float((rk >> 16) << 16);
    __hip_bfloat162 o;
    o.x = __float2bfloat16(h0);
    o.y = __float2bfloat16(h1);
    *(__hip_bfloat162*)&Hb[r * LDA + j] = o;
  }
  __syncthreads();

  // ---- diff WLN layer ----
  wln_layer(Hb, Tb, sEf, sRowPtr, sEidx, wf_msgd, bmsgd, WmdBot, wf_newd, bnewd,
            lane, gh, m0, mc, quad, l16, q8, c2);
  { bf16* tmp = Hb; Hb = Tb; Tb = tmp; }

  // ---- head: sum-pool + MLP + candidate score ----
  {
    int j = tid & 127, qq = tid >> 7;  // 4 row-groups of 25
    float p = 0.f;
    for (int v = qq * 25; v < qq * 25 + 25; ++v)
      p += __bfloat162float(Hb[v * LDA + j]);
    sRed[tid] = p;
  }
  __syncthreads();
  if (tid < H) {
    float s = 0.f;
#pragma unroll
    for (int q = 0; q < 4; ++q) s += sRed[q * 128 + tid];
    sG[tid] = s;
  }
  __syncthreads();
  {
    int j = tid & 127, qq = tid >> 7;
    float a = 0.f;
    for (int k = qq * 32; k < qq * 32 + 32; ++k)
      a = fmaf(sG[k], W1[(size_t)k * H + j], a);
    sRed[tid] = a;
  }
  __syncthreads();
  if (tid < H) {
    float m = b1[tid];
#pragma unroll
    for (int q = 0; q < 4; ++q) m += sRed[q * 128 + tid];
    sG[tid] = fmaxf(m, 0.f) * W2[tid];
  }
  __syncthreads();
  if (wave == 0) {
    float v = sG[lane] + sG[lane + 64];
#pragma unroll
    for (int d = 32; d > 0; d >>= 1) v += __shfl_down(v, d, 64);
    if (lane == 0) out[c] = v + b2[0] + scores[c];
  }
}

extern "C" void kernel_launch(void* const* d_in, const int* in_sizes, int n_in,
                              void* d_out, int out_size, void* d_ws, size_t ws_size,
                              hipStream_t stream) {
  const float* Xr  = (const float*)d_in[0];
  const float* Ere = (const float*)d_in[1];
  const float* Xp  = (const float*)d_in[2];
  const float* Epe = (const float*)d_in[3];
  const float* sc  = (const float*)d_in[4];
  const float* Wp  = (const float*)d_in[5];
  const float* bp  = (const float*)d_in[6];
  const float* Wm  = (const float*)d_in[7];
  const float* bm  = (const float*)d_in[8];
  const float* Wn  = (const float*)d_in[9];
  const float* bn  = (const float*)d_in[10];
  const float* Wmd = (const float*)d_in[11];
  const float* bmd = (const float*)d_in[12];
  const float* Wnd = (const float*)d_in[13];
  const float* bnd = (const float*)d_in[14];
  const float* W1  = (const float*)d_in[15];
  const float* b1  = (const float*)d_in[16];
  const float* W2  = (const float*)d_in[17];
  const float* b2  = (const float*)d_in[18];
  const int* rsrc  = (const int*)d_in[19];
  const int* rdst  = (const int*)d_in[20];
  const int* psrc  = (const int*)d_in[21];
  const int* pdst  = (const int*)d_in[22];

  bf16* wf_proj = (bf16*)d_ws;            // 27*4096 total frag elems
  bf16* wf_msg  = wf_proj + 3 * 4096;
  bf16* wf_new  = wf_msg + 4 * 4096;
  bf16* wf_msgd = wf_new + 8 * 4096;
  bf16* wf_newd = wf_msgd + 4 * 4096;
  bf16* hr      = wf_newd + 8 * 4096;     // VV*H
  int* flag     = (int*)(hr + VV * H);

  float* out = (float*)d_out;

  // ---- tiny prep: weight frags + flag ----
  prep_w<<<(PREP_W + 255) / 256, 256, 0, stream>>>(Wp, Wm, Wn, Wmd, Wnd,
                                                   wf_proj, flag);

  // ---- single dispatch: block 0 = reactant, blocks 1..1000 = products ----
  wln_fused<<<CC + 1, NT, 0, stream>>>(
      Xr, Ere, rsrc, rdst, Xp, Epe, psrc, pdst,
      wf_proj, bp, wf_msg, bm, Wm + H * H, wf_new, bn,
      wf_msgd, bmd, Wmd + H * H, wf_newd, bnd, hr, flag,
      W1, b1, W2, b2, sc, out);
}

// Round 13
// 256.000 us; speedup vs baseline: 1.3611x; 1.3611x over previous
//
#include <hip/hip_runtime.h>
#include <hip/hip_bf16.h>
#include <cstdint>

#define H 128
#define VV 100
#define CC 1000
#define ER_N 250
#define NODE_IN_N 82
#define EDGE_IN_N 6
#define LDA 136     // bf16 row stride: 272B rows, b128-aligned, 2-way banks (free)
#define NT 512      // 8 waves per block; 2 blocks/CU (LDS ~68KB, VGPR<=128)

typedef short short8 __attribute__((ext_vector_type(8)));
typedef float floatx4 __attribute__((ext_vector_type(4)));
typedef __hip_bfloat16 bf16;

// ---- shared memory layout (manual offsets, 16B aligned)
#define OFF_B0 0
#define OFF_B1 27200
#define OFF_EF 54400
#define OFF_RP 62400
#define OFF_CNT 62816
#define OFF_SD 63232
#define OFF_EIDX 64240
#define OFF_RED 65248
#define OFF_G 67296
#define SMEM_TOTAL 67808

// ================= prep: weights -> B-frag bf16 + flag reset (tiny) =================
#define PREP_W (27 * 4096)
__global__ __launch_bounds__(256) void prep_w(
    const float* __restrict__ Wp, const float* __restrict__ Wm,
    const float* __restrict__ Wn, const float* __restrict__ Wmd,
    const float* __restrict__ Wnd, bf16* __restrict__ wfrag,
    int* __restrict__ flag) {
  int idx = blockIdx.x * 256 + threadIdx.x;
  if (idx == 0) *flag = 0;  // hr-ready flag: ws is poisoned each call, must re-zero
  if (idx >= PREP_W) return;
  const float* W;
  int Ksrc, local = idx;
  if (idx < 3 * 4096)       { W = Wp;  Ksrc = NODE_IN_N; }
  else if (idx < 7 * 4096)  { W = Wm;  Ksrc = H;     local -= 3 * 4096; }
  else if (idx < 15 * 4096) { W = Wn;  Ksrc = 2 * H; local -= 7 * 4096; }
  else if (idx < 19 * 4096) { W = Wmd; Ksrc = H;     local -= 15 * 4096; }
  else                      { W = Wnd; Ksrc = 2 * H; local -= 19 * 4096; }
  int j = local & 7, lane = (local >> 3) & 63, nt = (local >> 9) & 7, kc = local >> 12;
  int k = kc * 32 + ((lane >> 4) & 3) * 8 + j;
  int n = nt * 16 + (lane & 15);
  float v = (k < Ksrc) ? W[(size_t)k * H + n] : 0.f;
  wfrag[idx] = __float2bfloat16(v);
}

// ====== GEMM helpers: wave = n-tile (0..7); each wave does all 7 m-tiles ======
// (R11-proven: 48 B-frag VGPRs + 56 acc VGPRs, fits 128 cap, no spill.
//  R12's A-reuse-2 mapping needs ~160 VGPRs -> spills. Do not revisit.)
template<int CHUNKS>
__device__ __forceinline__ void load_bfrag(short8 b[CHUNKS], const bf16* __restrict__ Wf,
                                           int nt8, int lane) {
#pragma unroll
  for (int kc = 0; kc < CHUNKS; ++kc)
    b[kc] = *(const short8*)(Wf + ((size_t)((kc * 8 + nt8) * 64 + lane)) * 8);
}

template<int CHUNKS>
__device__ __forceinline__ void mfma_m7(floatx4 acc[7], const short8 b[CHUNKS],
                                        const bf16* A, int l16, int quad) {
#pragma unroll
  for (int kc = 0; kc < CHUNKS; ++kc)
#pragma unroll
    for (int mi = 0; mi < 7; ++mi) {
      short8 a = *(const short8*)(A + (mi * 16 + l16) * LDA + kc * 32 + quad * 8);
      acc[mi] = __builtin_amdgcn_mfma_f32_16x16x32_bf16(a, b[kc], acc[mi], 0, 0, 0);
    }
}

__device__ __forceinline__ void epi(floatx4 acc[7], const float* __restrict__ bias,
                                    bool relu, bf16* Out, int nt8, int quad, int l16) {
  int col = nt8 * 16 + l16;
  float bb = bias[col];
#pragma unroll
  for (int mi = 0; mi < 7; ++mi)
#pragma unroll
    for (int r = 0; r < 4; ++r) {
      int row = mi * 16 + quad * 4 + r;
      if (row < VV) {
        float v = acc[mi][r] + bb;
        if (relu) v = fmaxf(v, 0.f);
        Out[row * LDA + col] = __float2bfloat16(v);
      }
    }
}

__device__ __forceinline__ void zero7(floatx4 acc[7]) {
#pragma unroll
  for (int mi = 0; mi < 7; ++mi) acc[mi] = (floatx4){0.f, 0.f, 0.f, 0.f};
}

// gather: thread (node q8+8i, col-pair c2) reads t(Y), writes agg directly into X
__device__ __forceinline__ void gather(const bf16* Y, bf16* X, const float* sEf,
                                       const int* sRowPtr, const int* sEidx,
                                       const float* __restrict__ WmBot,
                                       int q8, int c2) {
  float wb[EDGE_IN_N][2];
#pragma unroll
  for (int k = 0; k < EDGE_IN_N; ++k) {
    float2 w2 = *(const float2*)&WmBot[k * H + 2 * c2];
    wb[k][0] = w2.x;
    wb[k][1] = w2.y;
  }
#pragma unroll
  for (int i = 0; i < 13; ++i) {
    int n = q8 + 8 * i;
    if (n < VV) {
      int p0 = sRowPtr[n], p1 = sRowPtr[n + 1];
      float a0 = 0.f, a1 = 0.f;
      for (int p = p0; p < p1; ++p) {
        int v = sEidx[p];
        int s = v & 127, e = v >> 7;
        uint32_t tt = *(const uint32_t*)&Y[s * LDA + 2 * c2];
        float u0 = __uint_as_float((tt & 0xffffu) << 16);
        float u1 = __uint_as_float((tt >> 16) << 16);
        float4 ea = *(const float4*)&sEf[e * 8];
        float2 eb = *(const float2*)&sEf[e * 8 + 4];
        u0 = fmaf(ea.x, wb[0][0], u0); u1 = fmaf(ea.x, wb[0][1], u1);
        u0 = fmaf(ea.y, wb[1][0], u0); u1 = fmaf(ea.y, wb[1][1], u1);
        u0 = fmaf(ea.z, wb[2][0], u0); u1 = fmaf(ea.z, wb[2][1], u1);
        u0 = fmaf(ea.w, wb[3][0], u0); u1 = fmaf(ea.w, wb[3][1], u1);
        u0 = fmaf(eb.x, wb[4][0], u0); u1 = fmaf(eb.x, wb[4][1], u1);
        u0 = fmaf(eb.y, wb[5][0], u0); u1 = fmaf(eb.y, wb[5][1], u1);
        a0 += fmaxf(u0, 0.f);
        a1 += fmaxf(u1, 0.f);
      }
      __hip_bfloat162 pk;
      pk.x = __float2bfloat16(a0);
      pk.y = __float2bfloat16(a1);
      *(__hip_bfloat162*)&X[n * LDA + 2 * c2] = pk;
    }
  }
}

// one WLN layer: h in X on entry, h_new in Y on exit (caller swaps). 4 barriers.
__device__ __forceinline__ void wln_layer(
    bf16* X, bf16* Y, const float* sEf, const int* sRowPtr, const int* sEidx,
    const bf16* __restrict__ wf_msg, const float* __restrict__ bmsg,
    const float* __restrict__ WmBot,
    const bf16* __restrict__ wf_new, const float* __restrict__ bnew,
    int lane, int nt8, int quad, int l16, int q8, int c2) {
  short8 bm_[4], bu1[4], bu2[4];
  floatx4 accM[7], accU[7];
  // P1: msg GEMM t = h @ Wm_top + bm -> Y
  load_bfrag<4>(bm_, wf_msg, nt8, lane);
  zero7(accM);
  mfma_m7<4>(accM, bm_, X, l16, quad);
  load_bfrag<4>(bu1, wf_new, nt8, lane);            // prefetch upd-h B
  epi(accM, bmsg, false, Y, nt8, quad, l16);
  __syncthreads();  // bar A: t visible
  // P2a: upd-h GEMM (reads X)
  zero7(accU);
  mfma_m7<4>(accU, bu1, X, l16, quad);
  load_bfrag<4>(bu2, wf_new + 4 * 4096, nt8, lane); // prefetch upd-agg B
  __syncthreads();  // bar B: all X reads complete
  // P2b: gather (reads Y, writes agg -> X)
  gather(Y, X, sEf, sRowPtr, sEidx, WmBot, q8, c2);
  __syncthreads();  // bar C: agg visible
  // P3: upd-agg GEMM, h_new -> Y (t dead)
  mfma_m7<4>(accU, bu2, X, l16, quad);
  epi(accU, bnew, true, Y, nt8, quad, l16);
  __syncthreads();  // bar D: h_new visible
}

// grid = 1001: block 0 = reactant (publishes hr via agent-scope atomics + flag),
// blocks 1..1000 = products (spin on flag at the diff point only).
__global__ __launch_bounds__(NT, 4) void wln_fused(
    const float* __restrict__ Xr, const float* __restrict__ Ere,
    const int* __restrict__ rsrc, const int* __restrict__ rdst,
    const float* __restrict__ Xp, const float* __restrict__ Epe,
    const int* __restrict__ psrc, const int* __restrict__ pdst,
    const bf16* __restrict__ wf_proj, const float* __restrict__ bproj,
    const bf16* __restrict__ wf_msg, const float* __restrict__ bmsg,
    const float* __restrict__ WmBot,
    const bf16* __restrict__ wf_new, const float* __restrict__ bnew,
    const bf16* __restrict__ wf_msgd, const float* __restrict__ bmsgd,
    const float* __restrict__ WmdBot,
    const bf16* __restrict__ wf_newd, const float* __restrict__ bnewd,
    bf16* __restrict__ hr_global, int* __restrict__ flag,
    const float* __restrict__ W1, const float* __restrict__ b1,
    const float* __restrict__ W2, const float* __restrict__ b2,
    const float* __restrict__ scores, float* __restrict__ out) {
  __shared__ __align__(16) char smem[SMEM_TOTAL];
  bf16* sB0 = (bf16*)(smem + OFF_B0);
  bf16* sB1 = (bf16*)(smem + OFF_B1);
  float* sEf = (float*)(smem + OFF_EF);
  int* sRowPtr = (int*)(smem + OFF_RP);
  int* sCnt = (int*)(smem + OFF_CNT);
  int* sSD = (int*)(smem + OFF_SD);
  int* sEidx = (int*)(smem + OFF_EIDX);
  float* sRed = (float*)(smem + OFF_RED);
  float* sG = (float*)(smem + OFF_G);

  const int tid = threadIdx.x;
  const int lane = tid & 63;
  const int wave = tid >> 6;                // 0..7
  const int quad = (lane >> 4) & 3, l16 = lane & 15;
  const int nt8 = wave;                     // wave = n-tile
  const int q8 = tid >> 6, c2 = tid & 63;
  const bool REAC = (blockIdx.x == 0);
  const int c = REAC ? 0 : (blockIdx.x - 1);
  const int no = c * VV;
  const long eo = (long)c * ER_N;

  // ---- stage edges + counts + edge feats + X (raw fp32 -> bf16) ----
  if (tid < VV) sCnt[tid] = 0;
  __syncthreads();
  if (tid < ER_N) {
    int s, d;
    if (REAC) { s = rsrc[tid]; d = rdst[tid]; }
    else      { s = psrc[eo + tid] - no; d = pdst[eo + tid] - no; }
    sSD[tid] = (d << 16) | s;
    atomicAdd(&sCnt[d], 1);
  }
  {
    const float* Xsrc = REAC ? Xr : (Xp + (size_t)no * NODE_IN_N);
    const float* Esrc = REAC ? Ere : (Epe + (size_t)eo * EDGE_IN_N);
    for (int f = tid; f < ER_N * EDGE_IN_N; f += NT) {
      int e = f / EDGE_IN_N, k = f - e * EDGE_IN_N;
      sEf[e * 8 + k] = Esrc[f];
    }
    for (int f = tid; f < VV * NODE_IN_N; f += NT) {
      int r = f / NODE_IN_N, cc = f - r * NODE_IN_N;
      sB0[r * LDA + cc] = __float2bfloat16(Xsrc[f]);
    }
    for (int f = tid; f < VV * 14; f += NT) {  // zero-pad cols 82..95
      int r = f / 14, cc = NODE_IN_N + (f - r * 14);
      sB0[r * LDA + cc] = __float2bfloat16(0.f);
    }
  }
  __syncthreads();

  // ---- single-wave shuffle scan (exclusive prefix over 100 counts) ----
  if (wave == 0) {
    int c0 = sCnt[lane];
    int c1 = (lane + 64 < VV) ? sCnt[lane + 64] : 0;
    int v = c0;
#pragma unroll
    for (int d = 1; d < 64; d <<= 1) {
      int t = __shfl_up(v, d, 64);
      if (lane >= d) v += t;
    }
    int total0 = __shfl(v, 63, 64);
    int w = c1;
#pragma unroll
    for (int d = 1; d < 64; d <<= 1) {
      int t = __shfl_up(w, d, 64);
      if (lane >= d) w += t;
    }
    int ex0 = v - c0;
    int ex1 = total0 + w - c1;
    sRowPtr[lane] = ex0;
    sCnt[lane] = ex0;
    if (lane + 64 < VV) {
      sRowPtr[lane + 64] = ex1;
      sCnt[lane + 64] = ex1;
    }
    if (lane == 0) sRowPtr[VV] = ER_N;
  }
  __syncthreads();
  if (tid < ER_N) {
    int sd = sSD[tid];
    int p = atomicAdd(&sCnt[sd >> 16], 1);
    sEidx[p] = (sd & 0xffff) | (tid << 7);
  }
  __syncthreads();

  // ---- input projection: h = relu(X @ Wproj + bproj) : sB0 -> sB1 ----
  {
    short8 bp_[3];
    floatx4 acc[7];
    load_bfrag<3>(bp_, wf_proj, nt8, lane);
    zero7(acc);
    mfma_m7<3>(acc, bp_, sB0, l16, quad);
    epi(acc, bproj, true, sB1, nt8, quad, l16);
  }
  __syncthreads();

  bf16* Hb = sB1;
  bf16* Tb = sB0;

  // ---- 3 shared-weight encoder layers (ping-pong) ----
  for (int l = 0; l < 3; ++l) {
    wln_layer(Hb, Tb, sEf, sRowPtr, sEidx, wf_msg, bmsg, WmBot, wf_new, bnew,
              lane, nt8, quad, l16, q8, c2);
    bf16* tmp = Hb; Hb = Tb; Tb = tmp;
  }

  if (REAC) {
    // publish hr with agent-scope stores (visible across non-coherent XCD L2s)
    for (int f = tid; f < VV * H / 2; f += NT) {
      int r = f >> 6, j = (f & 63) * 2;
      uint32_t pk = *(const uint32_t*)&Hb[r * LDA + j];
      __hip_atomic_store((uint32_t*)hr_global + f, pk,
                         __ATOMIC_RELAXED, __HIP_MEMORY_SCOPE_AGENT);
    }
    __syncthreads();
    if (tid == 0)
      __hip_atomic_store(flag, 1, __ATOMIC_RELEASE, __HIP_MEMORY_SCOPE_AGENT);
    return;
  }

  // ---- wait for hr, then diff against broadcast reactant (in place on Hb) ----
  if (tid == 0) {
    while (__hip_atomic_load(flag, __ATOMIC_ACQUIRE, __HIP_MEMORY_SCOPE_AGENT) == 0)
      __builtin_amdgcn_s_sleep(16);
  }
  __syncthreads();
  for (int f = tid; f < VV * H / 2; f += NT) {
    int r = f >> 6, j = (f & 63) * 2;
    uint32_t rk = __hip_atomic_load((const uint32_t*)hr_global + f,
                                    __ATOMIC_RELAXED, __HIP_MEMORY_SCOPE_AGENT);
    uint32_t hk = *(const uint32_t*)&Hb[r * LDA + j];
    float h0 = __uint_as_float((hk & 0xffffu) << 16) -
               __uint_as_float((rk & 0xffffu) << 16);
    float h1 = __uint_as_float((hk >> 16) << 16) -
               __uint_as_float((rk >> 16) << 16);
    __hip_bfloat162 o;
    o.x = __float2bfloat16(h0);
    o.y = __float2bfloat16(h1);
    *(__hip_bfloat162*)&Hb[r * LDA + j] = o;
  }
  __syncthreads();

  // ---- diff WLN layer ----
  wln_layer(Hb, Tb, sEf, sRowPtr, sEidx, wf_msgd, bmsgd, WmdBot, wf_newd, bnewd,
            lane, nt8, quad, l16, q8, c2);
  { bf16* tmp = Hb; Hb = Tb; Tb = tmp; }

  // ---- head: sum-pool + MLP + candidate score ----
  {
    int j = tid & 127, qq = tid >> 7;  // 4 row-groups of 25
    float p = 0.f;
    for (int v = qq * 25; v < qq * 25 + 25; ++v)
      p += __bfloat162float(Hb[v * LDA + j]);
    sRed[tid] = p;
  }
  __syncthreads();
  if (tid < H) {
    float s = 0.f;
#pragma unroll
    for (int q = 0; q < 4; ++q) s += sRed[q * 128 + tid];
    sG[tid] = s;
  }
  __syncthreads();
  {
    int j = tid & 127, qq = tid >> 7;
    float a = 0.f;
    for (int k = qq * 32; k < qq * 32 + 32; ++k)
      a = fmaf(sG[k], W1[(size_t)k * H + j], a);
    sRed[tid] = a;
  }
  __syncthreads();
  if (tid < H) {
    float m = b1[tid];
#pragma unroll
    for (int q = 0; q < 4; ++q) m += sRed[q * 128 + tid];
    sG[tid] = fmaxf(m, 0.f) * W2[tid];
  }
  __syncthreads();
  if (wave == 0) {
    float v = sG[lane] + sG[lane + 64];
#pragma unroll
    for (int d = 32; d > 0; d >>= 1) v += __shfl_down(v, d, 64);
    if (lane == 0) out[c] = v + b2[0] + scores[c];
  }
}

extern "C" void kernel_launch(void* const* d_in, const int* in_sizes, int n_in,
                              void* d_out, int out_size, void* d_ws, size_t ws_size,
                              hipStream_t stream) {
  const float* Xr  = (const float*)d_in[0];
  const float* Ere = (const float*)d_in[1];
  const float* Xp  = (const float*)d_in[2];
  const float* Epe = (const float*)d_in[3];
  const float* sc  = (const float*)d_in[4];
  const float* Wp  = (const float*)d_in[5];
  const float* bp  = (const float*)d_in[6];
  const float* Wm  = (const float*)d_in[7];
  const float* bm  = (const float*)d_in[8];
  const float* Wn  = (const float*)d_in[9];
  const float* bn  = (const float*)d_in[10];
  const float* Wmd = (const float*)d_in[11];
  const float* bmd = (const float*)d_in[12];
  const float* Wnd = (const float*)d_in[13];
  const float* bnd = (const float*)d_in[14];
  const float* W1  = (const float*)d_in[15];
  const float* b1  = (const float*)d_in[16];
  const float* W2  = (const float*)d_in[17];
  const float* b2  = (const float*)d_in[18];
  const int* rsrc  = (const int*)d_in[19];
  const int* rdst  = (const int*)d_in[20];
  const int* psrc  = (const int*)d_in[21];
  const int* pdst  = (const int*)d_in[22];

  bf16* wf_proj = (bf16*)d_ws;            // 27*4096 total frag elems
  bf16* wf_msg  = wf_proj + 3 * 4096;
  bf16* wf_new  = wf_msg + 4 * 4096;
  bf16* wf_msgd = wf_new + 8 * 4096;
  bf16* wf_newd = wf_msgd + 4 * 4096;
  bf16* hr      = wf_newd + 8 * 4096;     // VV*H
  int* flag     = (int*)(hr + VV * H);

  float* out = (float*)d_out;

  // ---- tiny prep: weight frags + flag ----
  prep_w<<<(PREP_W + 255) / 256, 256, 0, stream>>>(Wp, Wm, Wn, Wmd, Wnd,
                                                   wf_proj, flag);

  // ---- single dispatch: block 0 = reactant, blocks 1..1000 = products ----
  wln_fused<<<CC + 1, NT, 0, stream>>>(
      Xr, Ere, rsrc, rdst, Xp, Epe, psrc, pdst,
      wf_proj, bp, wf_msg, bm, Wm + H * H, wf_new, bn,
      wf_msgd, bmd, Wmd + H * H, wf_newd, bnd, hr, flag,
      W1, b1, W2, b2, sc, out);
}